// Round 6
// baseline (275.843 us; speedup 1.0000x reference)
//
#include <hip/hip_runtime.h>

#define SQ 4096
#define SKV 1024
#define BATCH 4
#define NH 8
#define DH 64
#define QD 1024
#define CD 768
#define INNER 512

typedef _Float16 half8 __attribute__((ext_vector_type(8)));
typedef _Float16 half4v __attribute__((ext_vector_type(4)));
typedef float floatx4 __attribute__((ext_vector_type(4)));
typedef float f32x16 __attribute__((ext_vector_type(16)));
typedef unsigned int uint4v __attribute__((ext_vector_type(4)));

#define MFMA16(a, b, c) __builtin_amdgcn_mfma_f32_16x16x32_f16(a, b, c, 0, 0, 0)
#define MFMA32(a, b, c) __builtin_amdgcn_mfma_f32_32x32x16_f16(a, b, c, 0, 0, 0)

// v_permlane32_swap_b32: a' = {a.lo31, b.lo31}, b' = {a.hi31, b.hi31}
#define PLSWAP(a, b) asm("v_permlane32_swap_b32 %0, %1" : "+v"(a), "+v"(b))

// async global->LDS, 16B per lane; LDS dest = wave-uniform base + lane*16
#define GLD16(gptr, lptr)                                                            \
  __builtin_amdgcn_global_load_lds(                                                  \
      (const __attribute__((address_space(1))) unsigned int*)(const void*)(gptr),    \
      (__attribute__((address_space(3))) unsigned int*)(void*)(lptr), 16, 0, 0)

// ---------------------------------------------------------------- prep (cast + transposes)
// One launch: blocks [0, NCAST) cast x/ctx fp32->fp16 (2048 elems/block);
// blocks [NCAST, NCAST+4096) do the 4 weight transposes (z = (id-NCAST)>>10).
__global__ __launch_bounds__(256) void prep(const float* __restrict__ x,
                                            const float* __restrict__ ctx,
                                            const float* __restrict__ Wq,
                                            const float* __restrict__ Wk,
                                            const float* __restrict__ Wv,
                                            const float* __restrict__ Wo,
                                            _Float16* __restrict__ xh,
                                            _Float16* __restrict__ ctxh,
                                            _Float16* __restrict__ wqt,
                                            _Float16* __restrict__ wkvt,
                                            _Float16* __restrict__ wot) {
  __shared__ float tile[32][33];
  const size_t NX = (size_t)BATCH * SQ * QD;   // 16.7M (8192 blocks)
  const size_t NC = (size_t)BATCH * SKV * CD;  // 3.1M  (1536 blocks)
  const unsigned NCAST = (unsigned)((NX + NC) / 2048);

  if (blockIdx.x < NCAST) {  // -------- cast path
    size_t i = ((size_t)blockIdx.x * 256 + threadIdx.x) * 8;
    const float* s;
    _Float16* d;
    size_t off;
    if (i < NX) { s = x; d = xh; off = i; }
    else        { s = ctx; d = ctxh; off = i - NX; }
    floatx4 a = *(const floatx4*)(s + off);
    floatx4 b = *(const floatx4*)(s + off + 4);
    half8 h;
#pragma unroll
    for (int j = 0; j < 4; ++j) { h[j] = (_Float16)a[j]; h[4 + j] = (_Float16)b[j]; }
    *(half8*)(d + off) = h;
    return;
  }
  // -------- transpose path: src [R,C] fp32 -> dst [C,R] fp16
  const unsigned t = blockIdx.x - NCAST;
  const int z = t >> 10, rem = t & 1023;
  const float* src; _Float16* dst; int R, C;
  if (z == 0)      { src = Wq; dst = wqt;                        R = QD;    C = INNER; }
  else if (z == 1) { src = Wk; dst = wkvt;                       R = CD;    C = INNER; }
  else if (z == 2) { src = Wv; dst = wkvt + (size_t)INNER * CD;  R = CD;    C = INNER; }
  else             { src = Wo; dst = wot;                        R = INNER; C = QD;   }
  const int c0 = (rem & 31) * 32, r0 = (rem >> 5) * 32;
  if (c0 >= C || r0 >= R) return;
  const int tx = threadIdx.x & 31, ty = threadIdx.x >> 5;
#pragma unroll
  for (int i = 0; i < 32; i += 8)
    tile[ty + i][tx] = src[(size_t)(r0 + ty + i) * C + c0 + tx];
  __syncthreads();
#pragma unroll
  for (int i = 0; i < 32; i += 8)
    dst[(size_t)(c0 + ty + i) * R + r0 + tx] = (_Float16)tile[tx][ty + i];
}

// ---------------------------------------------------------------- dbuf GEMM body
// C[M,N] = A[M,K] @ B[K,N], A row-major fp16, B transposed (Bt[N,K], fp16).
// Tile 128x128, BK=32, 4 waves (2x2 of 64x64). DOUBLE-BUFFERED LDS with ONE
// barrier per k-step: prefetch(t+1) issued right after the barrier, drained at the
// NEXT barrier -> load latency covered by a full compute phase (flash_attn7's
// proven pattern; the old 2-barrier loop exposed the full vmcnt(0) drain per step).
// MODE 2: fp32 + bias. MODE 3: fp16 out scaled by 0.125*log2(e).
// MODE 4: merged k/v epilogue — n<512 -> kh row-major [M,512]; n>=512 -> vT scatter.
template <int MODE>
__device__ __forceinline__ void gemm_body(const _Float16* __restrict__ A,
                                          const _Float16* __restrict__ Bt,
                                          void* __restrict__ Cout,
                                          void* __restrict__ Cout2,
                                          const float* __restrict__ bias,
                                          int M, int N, int K, int bx, int by,
                                          _Float16* As16, _Float16* Bs) {
  const int tid = threadIdx.x;
  const int wave = tid >> 6, lane = tid & 63;
  const int quad = lane >> 4, l16 = lane & 15;
  const int wm = (wave >> 1) * 64, wn = (wave & 1) * 64;
  const size_t n0 = (size_t)bx * 128, m0 = (size_t)by * 128;

  floatx4 acc[4][4] = {};

  const _Float16* ag = A + (m0 + (tid >> 2)) * (size_t)K + (tid & 3) * 8;
  const _Float16* bg = Bt + (n0 + (tid >> 2)) * (size_t)K + (tid & 3) * 8;

#define GSTAGE(bi, k0)                                                      \
  do {                                                                      \
    GLD16(ag + (k0), As16 + (bi)*4096 + tid * 8);                           \
    GLD16(ag + (k0) + (size_t)64 * K, As16 + (bi)*4096 + tid * 8 + 2048);   \
    GLD16(bg + (k0), Bs + (bi)*4096 + tid * 8);                             \
    GLD16(bg + (k0) + (size_t)64 * K, Bs + (bi)*4096 + tid * 8 + 2048);     \
  } while (0)

  const int NT = K / 32;
  GSTAGE(0, 0);
  for (int t = 0; t < NT; ++t) {
    __syncthreads();  // drains tile-t loads (issued one compute phase ago);
                      // also fences: prev readers of buf[(t+1)&1] are done
    if (t + 1 < NT) GSTAGE((t + 1) & 1, (t + 1) * 32);
    const _Float16* as = As16 + (t & 1) * 4096;
    const _Float16* bs = Bs + (t & 1) * 4096;

    half8 af[4], bf[4];
#pragma unroll
    for (int mt = 0; mt < 4; ++mt)
      af[mt] = *(const half8*)(as + (wm + mt * 16 + l16) * 32 + quad * 8);
#pragma unroll
    for (int nt = 0; nt < 4; ++nt)
      bf[nt] = *(const half8*)(bs + (wn + nt * 16 + l16) * 32 + quad * 8);
    __builtin_amdgcn_s_setprio(1);
#pragma unroll
    for (int mt = 0; mt < 4; ++mt)
#pragma unroll
      for (int nt = 0; nt < 4; ++nt)
        acc[mt][nt] = MFMA16(af[mt], bf[nt], acc[mt][nt]);
    __builtin_amdgcn_s_setprio(0);
  }
#undef GSTAGE

  // epilogue: C/D layout row = quad*4+r, col = l16
  if (MODE == 3) {
    _Float16* C = (_Float16*)Cout;
    // fold softmax scale (1/8) and log2(e) into Q so attention uses exp2
    const float sc = 0.125f * 1.44269504088896f;
#pragma unroll
    for (int mt = 0; mt < 4; ++mt) {
      const size_t row = m0 + wm + mt * 16 + quad * 4;
#pragma unroll
      for (int nt = 0; nt < 4; ++nt) {
        const size_t col = n0 + wn + nt * 16 + l16;
#pragma unroll
        for (int r = 0; r < 4; ++r)
          C[(row + r) * N + col] = (_Float16)(acc[mt][nt][r] * sc);
      }
    }
  } else if (MODE == 4) {
    if (n0 < INNER) {  // K half: row-major [M, INNER]
      _Float16* C = (_Float16*)Cout;
#pragma unroll
      for (int mt = 0; mt < 4; ++mt) {
        const size_t row = m0 + wm + mt * 16 + quad * 4;
#pragma unroll
        for (int nt = 0; nt < 4; ++nt) {
          const size_t col = n0 + wn + nt * 16 + l16;
#pragma unroll
          for (int r = 0; r < 4; ++r)
            C[(row + r) * INNER + col] = (_Float16)acc[mt][nt][r];
        }
      }
    } else {  // V half: scatter to vT[b][h][d][kv]
      _Float16* C = (_Float16*)Cout2;
      const int b = (int)(m0 >> 10);
#pragma unroll
      for (int mt = 0; mt < 4; ++mt) {
        const int kvb = (int)(m0 & 1023) + wm + mt * 16 + quad * 4;
#pragma unroll
        for (int nt = 0; nt < 4; ++nt) {
          const int col = (int)(n0 - INNER + wn + nt * 16 + l16);
          const int h = col >> 6, d = col & 63;
          half4v pk;
#pragma unroll
          for (int r = 0; r < 4; ++r) pk[r] = (_Float16)acc[mt][nt][r];
          *(half4v*)(C + (size_t)((b * NH + h) * DH + d) * SKV + kvb) = pk;
        }
      }
    }
  } else {
    float* C = (float*)Cout;
#pragma unroll
    for (int mt = 0; mt < 4; ++mt) {
      const size_t row = m0 + wm + mt * 16 + quad * 4;
#pragma unroll
      for (int nt = 0; nt < 4; ++nt) {
        const size_t col = n0 + wn + nt * 16 + l16;
        const float bb = bias[col];
#pragma unroll
        for (int r = 0; r < 4; ++r)
          C[(row + r) * N + col] = acc[mt][nt][r] + bb;
      }
    }
  }
}

// ---------------------------------------------------------------- fused projections
// Q-proj (512 blocks) + KV-proj (256 blocks) in ONE 768-block launch, interleaved
// mod 3 so every CU holds a mix (~3 blocks/CU of mutually-overlapping schedules).
__global__ __launch_bounds__(256) void proj_fused(const _Float16* __restrict__ xh,
                                                  const _Float16* __restrict__ ctxh,
                                                  const _Float16* __restrict__ wqt,
                                                  const _Float16* __restrict__ wkvt,
                                                  _Float16* __restrict__ qh,
                                                  _Float16* __restrict__ kh,
                                                  _Float16* __restrict__ vth) {
  __shared__ _Float16 As16[2 * 128 * 32];
  __shared__ _Float16 Bs[2 * 128 * 32];
  const int id = blockIdx.x;
  const int seg = id % 3, base = id / 3;
  if (seg == 2) {  // KV: M=4096, N=1024 (k|v), K=768
    gemm_body<4>(ctxh, wkvt, kh, vth, nullptr, BATCH * SKV, 2 * INNER, CD,
                 base & 7, base >> 3, As16, Bs);
  } else {  // Q: M=16384, N=512, K=1024 (scale folded)
    const int q = base * 2 + seg;
    gemm_body<3>(xh, wqt, qh, nullptr, nullptr, BATCH * SQ, INNER, QD,
                 q & 3, q >> 2, As16, Bs);
  }
}

// ---------------------------------------------------------------- output projection
__global__ __launch_bounds__(256) void gemm_out(const _Float16* __restrict__ A,
                                                const _Float16* __restrict__ Bt,
                                                float* __restrict__ Cout,
                                                const float* __restrict__ bias) {
  __shared__ _Float16 As16[2 * 128 * 32];
  __shared__ _Float16 Bs[2 * 128 * 32];
  gemm_body<2>(A, Bt, Cout, nullptr, bias, BATCH * SQ, QD, INNER,
               blockIdx.x, blockIdx.y, As16, Bs);
}

// ---------------------------------------------------------------- flash attention v7
// 32x32x16 MFMA. Swapped QK^T (S^T = K·Q^T): lane owns one q-row, softmax lane-local;
// P->PV-A transpose = 4 v_permlane32_swap_b32; row-sums via ones-MFMA (same layout as
// o -> lane-local normalize). KV-tile 64, double-buffered LDS, one barrier per tile,
// prefetch-before-compute. XOR-swizzled tiles (blk ^= row&7) with pre-swizzled global
// source (gload_lds dest stays linear). Grid 1024, XCD swizzle.
__global__ __launch_bounds__(256, 3) void flash_attn7(const _Float16* __restrict__ Q,
                                                      const _Float16* __restrict__ Kp,
                                                      const _Float16* __restrict__ Vt,
                                                      _Float16* __restrict__ O) {
  __shared__ _Float16 Ksb[2 * 64 * 64];  // [buf][kv64][d64], 16B-blk XOR by kv&7
  __shared__ _Float16 Vsb[2 * 64 * 64];  // [buf][d64][kv64], 16B-blk XOR by d&7
  const int tid = threadIdx.x;
  const int wave = tid >> 6, lane = tid & 63;
  const int l31 = lane & 31, hi = lane >> 5, x7 = lane & 7;

  // XCD-aware swizzle: 1024 blocks % 8 == 0 -> bijective chunked remap
  const int flat = blockIdx.x;
  const int nf = (flat & 7) * 128 + (flat >> 3);
  const int qblk = nf & 31, bh = nf >> 5;
  const int b = bh >> 3, h = bh & 7;

  const size_t qrow0 = (size_t)b * SQ + qblk * 128 + wave * 32;
  const _Float16* qptr = Q + qrow0 * INNER + h * DH;
  const _Float16* kbase = Kp + (size_t)b * SKV * INNER + h * DH;
  const _Float16* vbase = Vt + (size_t)bh * DH * SKV;

  // staging: linear LDS dest (tid*16B), pre-swizzled global src (blk ^= row&7)
  const int kr = tid >> 3;
  const int kb = (tid & 7) ^ (kr & 7);
  const _Float16* kg = kbase + (size_t)kr * INNER + kb * 8;
  const _Float16* vg = vbase + (size_t)kr * SKV + kb * 8;

#define STAGE_KV(bi, tt)                                                        \
  do {                                                                          \
    _Float16* _kl = Ksb + (bi) * 4096 + tid * 8;                                \
    _Float16* _vl = Vsb + (bi) * 4096 + tid * 8;                                \
    GLD16(kg + (size_t)((tt) * 64) * INNER, _kl);                               \
    GLD16(kg + (size_t)((tt) * 64 + 32) * INNER, _kl + 2048);                   \
    GLD16(vg + (tt) * 64, _vl);                                                 \
    GLD16(vg + (size_t)32 * SKV + (tt) * 64, _vl + 2048);                       \
  } while (0)

  half8 aq[4];
#pragma unroll
  for (int i = 0; i < 4; ++i)
    aq[i] = *(const half8*)(qptr + (size_t)l31 * INNER + i * 16 + hi * 8);

  int koff[4], voffB[4];
#pragma unroll
  for (int i = 0; i < 4; ++i)
    koff[i] = l31 * 64 + (((i * 2 + hi) ^ x7) << 3);
#pragma unroll
  for (int j = 0; j < 4; ++j)
    voffB[j] = l31 * 64 + (((j * 2 + hi) ^ x7) << 3);

  half8 ones;
#pragma unroll
  for (int j = 0; j < 8; ++j) ones[j] = (_Float16)1.0f;

  f32x16 o0 = {}, o1 = {}, osum = {};

  STAGE_KV(0, 0);

  for (int t = 0; t < SKV / 64; ++t) {
    __syncthreads();
    if (t < SKV / 64 - 1) STAGE_KV((t + 1) & 1, t + 1);
    const _Float16* ks = Ksb + (t & 1) * 4096;
    const _Float16* vs = Vsb + (t & 1) * 4096;

#pragma unroll
    for (int c2 = 0; c2 < 2; ++c2) {
      half8 ak[4];
#pragma unroll
      for (int i = 0; i < 4; ++i)
        ak[i] = *(const half8*)(ks + c2 * 2048 + koff[i]);

      f32x16 st = {};
      __builtin_amdgcn_s_setprio(1);
#pragma unroll
      for (int i = 0; i < 4; ++i) st = MFMA32(ak[i], aq[i], st);
      __builtin_amdgcn_s_setprio(0);

      unsigned w[8];
#pragma unroll
      for (int j = 0; j < 8; ++j) {
        float plo = __builtin_exp2f(st[2 * j]);
        float phi = __builtin_exp2f(st[2 * j + 1]);
        w[j] = __builtin_bit_cast(unsigned, __builtin_amdgcn_cvt_pkrtz(plo, phi));
      }
      PLSWAP(w[0], w[2]);
      PLSWAP(w[1], w[3]);
      PLSWAP(w[4], w[6]);
      PLSWAP(w[5], w[7]);
      uint4v u0 = {w[0], w[1], w[2], w[3]};
      uint4v u1 = {w[4], w[5], w[6], w[7]};
      half8 A0 = __builtin_bit_cast(half8, u0);
      half8 A1 = __builtin_bit_cast(half8, u1);

      __builtin_amdgcn_s_setprio(1);
      osum = MFMA32(A0, ones, osum);
      osum = MFMA32(A1, ones, osum);

      {
        half8 bv00 = *(const half8*)(vs + 0 * 2048 + voffB[c2 * 2 + 0]);
        half8 bv10 = *(const half8*)(vs + 1 * 2048 + voffB[c2 * 2 + 0]);
        o0 = MFMA32(A0, bv00, o0);
        o1 = MFMA32(A0, bv10, o1);
        half8 bv01 = *(const half8*)(vs + 0 * 2048 + voffB[c2 * 2 + 1]);
        half8 bv11 = *(const half8*)(vs + 1 * 2048 + voffB[c2 * 2 + 1]);
        o0 = MFMA32(A1, bv01, o0);
        o1 = MFMA32(A1, bv11, o1);
      }
      __builtin_amdgcn_s_setprio(0);
    }
  }

  float inv16[16];
#pragma unroll
  for (int r = 0; r < 16; ++r) inv16[r] = 1.0f / osum[r];

  _Float16* op = O + qrow0 * INNER + h * DH;
#pragma unroll
  for (int r = 0; r < 16; ++r) {
    const int q = (r & 3) + 8 * (r >> 2) + 4 * hi;
    op[(size_t)q * INNER + l31] = (_Float16)(o0[r] * inv16[r]);
    op[(size_t)q * INNER + 32 + l31] = (_Float16)(o1[r] * inv16[r]);
  }
#undef STAGE_KV
}

// ---------------------------------------------------------------- launcher
extern "C" void kernel_launch(void* const* d_in, const int* in_sizes, int n_in,
                              void* d_out, int out_size, void* d_ws, size_t ws_size,
                              hipStream_t stream) {
  const float* x   = (const float*)d_in[0];
  const float* ctx = (const float*)d_in[1];
  const float* Wq  = (const float*)d_in[2];
  const float* Wk  = (const float*)d_in[3];
  const float* Wv  = (const float*)d_in[4];
  const float* Wo  = (const float*)d_in[5];
  const float* bo  = (const float*)d_in[6];
  float* out = (float*)d_out;

  const size_t NX = (size_t)BATCH * SQ * QD;   // 16.7M
  const size_t NC = (size_t)BATCH * SKV * CD;  // 3.1M

  _Float16* ws = (_Float16*)d_ws;
  _Float16* xh   = ws;                                   // [16384,1024] fp16
  _Float16* ctxh = xh + NX;                              // [4096,768]
  _Float16* wqt  = ctxh + NC;                            // [512,1024]
  _Float16* wkvt = wqt + (size_t)INNER * QD;             // [1024,768] (k rows, then v)
  _Float16* wot  = wkvt + (size_t)2 * INNER * CD;        // [1024,512]
  _Float16* qh   = wot + (size_t)QD * INNER;             // [16384,512]
  _Float16* kh   = qh + (size_t)BATCH * SQ * INNER;      // [4096,512]
  _Float16* vth  = kh + (size_t)BATCH * SKV * INNER;     // [4,8,64,1024]
  _Float16* aoh  = xh;  // alias: xh dead after proj_fused; aoh (8.4M) fits in NX

  // cast (9728 blocks) + weight transposes (4096 blocks) in one launch
  prep<<<dim3((unsigned)((NX + NC) / 2048) + 4096), 256, 0, stream>>>(
      x, ctx, Wq, Wk, Wv, Wo, xh, ctxh, wqt, wkvt, wot);

  // fused Q + KV projections (768 blocks, mod-3 interleaved)
  proj_fused<<<dim3(768), 256, 0, stream>>>(xh, ctxh, wqt, wkvt, qh, kh, vth);

  // attention
  flash_attn7<<<dim3(BATCH * NH * SQ / 128), 256, 0, stream>>>(qh, kh, vth, aoh);

  // output projection + bias, fp32 out
  gemm_out<<<dim3(QD / 128, BATCH * SQ / 128), 256, 0, stream>>>(aoh, wot, out, bo);
}

// Round 8
// 262.364 us; speedup vs baseline: 1.0514x; 1.0514x over previous
//
#include <hip/hip_runtime.h>

#define SQ 4096
#define SKV 1024
#define BATCH 4
#define NH 8
#define DH 64
#define QD 1024
#define CD 768
#define INNER 512

typedef _Float16 half8 __attribute__((ext_vector_type(8)));
typedef _Float16 half4v __attribute__((ext_vector_type(4)));
typedef float floatx4 __attribute__((ext_vector_type(4)));
typedef float f32x16 __attribute__((ext_vector_type(16)));
typedef unsigned int uint4v __attribute__((ext_vector_type(4)));

#define MFMA16(a, b, c) __builtin_amdgcn_mfma_f32_16x16x32_f16(a, b, c, 0, 0, 0)
#define MFMA32(a, b, c) __builtin_amdgcn_mfma_f32_32x32x16_f16(a, b, c, 0, 0, 0)

// v_permlane32_swap_b32: a' = {a.lo31, b.lo31}, b' = {a.hi31, b.hi31}
#define PLSWAP(a, b) asm("v_permlane32_swap_b32 %0, %1" : "+v"(a), "+v"(b))

// async global->LDS, 16B per lane; LDS dest = wave-uniform base + lane*16
#define GLD16(gptr, lptr)                                                            \
  __builtin_amdgcn_global_load_lds(                                                  \
      (const __attribute__((address_space(1))) unsigned int*)(const void*)(gptr),    \
      (__attribute__((address_space(3))) unsigned int*)(void*)(lptr), 16, 0, 0)

// ---------------------------------------------------------------- prep (cast + transposes)
// One launch: blocks [0, NCAST) cast x/ctx fp32->fp16 (2048 elems/block);
// blocks [NCAST, NCAST+4096) do the 4 weight transposes (z = (id-NCAST)>>10).
__global__ __launch_bounds__(256) void prep(const float* __restrict__ x,
                                            const float* __restrict__ ctx,
                                            const float* __restrict__ Wq,
                                            const float* __restrict__ Wk,
                                            const float* __restrict__ Wv,
                                            const float* __restrict__ Wo,
                                            _Float16* __restrict__ xh,
                                            _Float16* __restrict__ ctxh,
                                            _Float16* __restrict__ wqt,
                                            _Float16* __restrict__ wkvt,
                                            _Float16* __restrict__ wot) {
  __shared__ float tile[32][33];
  const size_t NX = (size_t)BATCH * SQ * QD;   // 16.7M (8192 blocks)
  const size_t NC = (size_t)BATCH * SKV * CD;  // 3.1M  (1536 blocks)
  const unsigned NCAST = (unsigned)((NX + NC) / 2048);

  if (blockIdx.x < NCAST) {  // -------- cast path
    size_t i = ((size_t)blockIdx.x * 256 + threadIdx.x) * 8;
    const float* s;
    _Float16* d;
    size_t off;
    if (i < NX) { s = x; d = xh; off = i; }
    else        { s = ctx; d = ctxh; off = i - NX; }
    floatx4 a = *(const floatx4*)(s + off);
    floatx4 b = *(const floatx4*)(s + off + 4);
    half8 h;
#pragma unroll
    for (int j = 0; j < 4; ++j) { h[j] = (_Float16)a[j]; h[4 + j] = (_Float16)b[j]; }
    *(half8*)(d + off) = h;
    return;
  }
  // -------- transpose path: src [R,C] fp32 -> dst [C,R] fp16
  const unsigned t = blockIdx.x - NCAST;
  const int z = t >> 10, rem = t & 1023;
  const float* src; _Float16* dst; int R, C;
  if (z == 0)      { src = Wq; dst = wqt;                        R = QD;    C = INNER; }
  else if (z == 1) { src = Wk; dst = wkvt;                       R = CD;    C = INNER; }
  else if (z == 2) { src = Wv; dst = wkvt + (size_t)INNER * CD;  R = CD;    C = INNER; }
  else             { src = Wo; dst = wot;                        R = INNER; C = QD;   }
  const int c0 = (rem & 31) * 32, r0 = (rem >> 5) * 32;
  if (c0 >= C || r0 >= R) return;
  const int tx = threadIdx.x & 31, ty = threadIdx.x >> 5;
#pragma unroll
  for (int i = 0; i < 32; i += 8)
    tile[ty + i][tx] = src[(size_t)(r0 + ty + i) * C + c0 + tx];
  __syncthreads();
#pragma unroll
  for (int i = 0; i < 32; i += 8)
    dst[(size_t)(c0 + ty + i) * R + r0 + tx] = (_Float16)tile[tx][ty + i];
}

// ---------------------------------------------------------------- dbuf GEMM body
// C[M,N] = A[M,K] @ B[K,N], A row-major fp16, B transposed (Bt[N,K], fp16).
// Tile 128x128, BK=32, 4 waves (2x2 of 64x64). Double-buffered LDS, one barrier
// per k-step, prefetch-before-compute (r6-green config).
// Callers pass bx/by — block mapping is XCD-LOCAL (see launch sites): all n-blocks
// of one A-stripe land on the SAME XCD so its private L2 fetches the stripe once.
// MODE 2: fp32 + bias. MODE 3: fp16 out scaled by 0.125*log2(e).
// MODE 4: merged k/v epilogue — n<512 -> kh row-major [M,512]; n>=512 -> vT scatter.
template <int MODE>
__device__ __forceinline__ void gemm_body(const _Float16* __restrict__ A,
                                          const _Float16* __restrict__ Bt,
                                          void* __restrict__ Cout,
                                          void* __restrict__ Cout2,
                                          const float* __restrict__ bias,
                                          int M, int N, int K, int bx, int by,
                                          _Float16* As16, _Float16* Bs) {
  const int tid = threadIdx.x;
  const int wave = tid >> 6, lane = tid & 63;
  const int quad = lane >> 4, l16 = lane & 15;
  const int wm = (wave >> 1) * 64, wn = (wave & 1) * 64;
  const size_t n0 = (size_t)bx * 128, m0 = (size_t)by * 128;

  floatx4 acc[4][4] = {};

  const _Float16* ag = A + (m0 + (tid >> 2)) * (size_t)K + (tid & 3) * 8;
  const _Float16* bg = Bt + (n0 + (tid >> 2)) * (size_t)K + (tid & 3) * 8;

#define GSTAGE(bi, k0)                                                      \
  do {                                                                      \
    GLD16(ag + (k0), As16 + (bi)*4096 + tid * 8);                           \
    GLD16(ag + (k0) + (size_t)64 * K, As16 + (bi)*4096 + tid * 8 + 2048);   \
    GLD16(bg + (k0), Bs + (bi)*4096 + tid * 8);                             \
    GLD16(bg + (k0) + (size_t)64 * K, Bs + (bi)*4096 + tid * 8 + 2048);     \
  } while (0)

  const int NT = K / 32;
  GSTAGE(0, 0);
  for (int t = 0; t < NT; ++t) {
    __syncthreads();  // drains tile-t loads (issued one compute phase ago);
                      // also fences: prev readers of buf[(t+1)&1] are done
    if (t + 1 < NT) GSTAGE((t + 1) & 1, (t + 1) * 32);
    const _Float16* as = As16 + (t & 1) * 4096;
    const _Float16* bs = Bs + (t & 1) * 4096;

    half8 af[4], bf[4];
#pragma unroll
    for (int mt = 0; mt < 4; ++mt)
      af[mt] = *(const half8*)(as + (wm + mt * 16 + l16) * 32 + quad * 8);
#pragma unroll
    for (int nt = 0; nt < 4; ++nt)
      bf[nt] = *(const half8*)(bs + (wn + nt * 16 + l16) * 32 + quad * 8);
    __builtin_amdgcn_s_setprio(1);
#pragma unroll
    for (int mt = 0; mt < 4; ++mt)
#pragma unroll
      for (int nt = 0; nt < 4; ++nt)
        acc[mt][nt] = MFMA16(af[mt], bf[nt], acc[mt][nt]);
    __builtin_amdgcn_s_setprio(0);
  }
#undef GSTAGE

  // epilogue: C/D layout row = quad*4+r, col = l16
  if (MODE == 3) {
    _Float16* C = (_Float16*)Cout;
    // fold softmax scale (1/8) and log2(e) into Q so attention uses exp2
    const float sc = 0.125f * 1.44269504088896f;
#pragma unroll
    for (int mt = 0; mt < 4; ++mt) {
      const size_t row = m0 + wm + mt * 16 + quad * 4;
#pragma unroll
      for (int nt = 0; nt < 4; ++nt) {
        const size_t col = n0 + wn + nt * 16 + l16;
#pragma unroll
        for (int r = 0; r < 4; ++r)
          C[(row + r) * N + col] = (_Float16)(acc[mt][nt][r] * sc);
      }
    }
  } else if (MODE == 4) {
    if (n0 < INNER) {  // K half: row-major [M, INNER]
      _Float16* C = (_Float16*)Cout;
#pragma unroll
      for (int mt = 0; mt < 4; ++mt) {
        const size_t row = m0 + wm + mt * 16 + quad * 4;
#pragma unroll
        for (int nt = 0; nt < 4; ++nt) {
          const size_t col = n0 + wn + nt * 16 + l16;
#pragma unroll
          for (int r = 0; r < 4; ++r)
            C[(row + r) * INNER + col] = (_Float16)acc[mt][nt][r];
        }
      }
    } else {  // V half: scatter to vT[b][h][d][kv]
      _Float16* C = (_Float16*)Cout2;
      const int b = (int)(m0 >> 10);
#pragma unroll
      for (int mt = 0; mt < 4; ++mt) {
        const int kvb = (int)(m0 & 1023) + wm + mt * 16 + quad * 4;
#pragma unroll
        for (int nt = 0; nt < 4; ++nt) {
          const int col = (int)(n0 - INNER + wn + nt * 16 + l16);
          const int h = col >> 6, d = col & 63;
          half4v pk;
#pragma unroll
          for (int r = 0; r < 4; ++r) pk[r] = (_Float16)acc[mt][nt][r];
          *(half4v*)(C + (size_t)((b * NH + h) * DH + d) * SKV + kvb) = pk;
        }
      }
    }
  } else {
    float* C = (float*)Cout;
#pragma unroll
    for (int mt = 0; mt < 4; ++mt) {
      const size_t row = m0 + wm + mt * 16 + quad * 4;
#pragma unroll
      for (int nt = 0; nt < 4; ++nt) {
        const size_t col = n0 + wn + nt * 16 + l16;
        const float bb = bias[col];
#pragma unroll
        for (int r = 0; r < 4; ++r)
          C[(row + r) * N + col] = acc[mt][nt][r] + bb;
      }
    }
  }
}

// ---------------------------------------------------------------- fused projections
// Q-proj (512 blocks) + KV-proj (256 blocks) in one 768-block launch.
// XCD-local mapping: xcd = b&7 (HW round-robin), j = b>>3 (0..95 within XCD).
// Within each XCD, j%3 interleaves {Q,Q,KV} (CU-level mix) and the XCD owns a
// contiguous band of m-stripes: Q stripes [xcd*16, xcd*16+16), KV [xcd*4, xcd*4+4)
// -> each A-stripe's n-blocks share ONE private L2 (fetch once, not 4-8x).
// Bijectivity: per xcd, Q jq=2*(j/3)+j%3 covers 0..63 -> (jq&3, jq>>2) unique;
// KV jkv=j/3 covers 0..31 -> (jkv&7, jkv>>3) unique. 8 xcds x disjoint by-bands.
__global__ __launch_bounds__(256) void proj_fused(const _Float16* __restrict__ xh,
                                                  const _Float16* __restrict__ ctxh,
                                                  const _Float16* __restrict__ wqt,
                                                  const _Float16* __restrict__ wkvt,
                                                  _Float16* __restrict__ qh,
                                                  _Float16* __restrict__ kh,
                                                  _Float16* __restrict__ vth) {
  __shared__ _Float16 As16[2 * 128 * 32];
  __shared__ _Float16 Bs[2 * 128 * 32];
  const int b = blockIdx.x;
  const int xcd = b & 7, j = b >> 3;
  const int seg = j % 3;
  if (seg == 2) {  // KV: M=4096, N=1024 (k|v), K=768; stripes 0..31, n 0..7
    const int jkv = j / 3;  // 0..31
    gemm_body<4>(ctxh, wkvt, kh, vth, nullptr, BATCH * SKV, 2 * INNER, CD,
                 jkv & 7, xcd * 4 + (jkv >> 3), As16, Bs);
  } else {  // Q: M=16384, N=512, K=1024 (scale folded); stripes 0..127, n 0..3
    const int jq = (j / 3) * 2 + seg;  // 0..63
    gemm_body<3>(xh, wqt, qh, nullptr, nullptr, BATCH * SQ, INNER, QD,
                 jq & 3, xcd * 16 + (jq >> 2), As16, Bs);
  }
}

// ---------------------------------------------------------------- output projection
// 1024 blocks, XCD-local: xcd = b&7 owns aoh m-stripes [xcd*16, xcd*16+16).
__global__ __launch_bounds__(256) void gemm_out(const _Float16* __restrict__ A,
                                                const _Float16* __restrict__ Bt,
                                                float* __restrict__ Cout,
                                                const float* __restrict__ bias) {
  __shared__ _Float16 As16[2 * 128 * 32];
  __shared__ _Float16 Bs[2 * 128 * 32];
  const int b = blockIdx.x;
  const int xcd = b & 7, i = b >> 3;  // i: 0..127
  gemm_body<2>(A, Bt, Cout, nullptr, bias, BATCH * SQ, QD, INNER,
               i & 7, xcd * 16 + (i >> 3), As16, Bs);
}

// ---------------------------------------------------------------- flash attention v8
// 32x32x16 MFMA. Swapped QK^T (S^T = K·Q^T): lane owns one q-row, softmax lane-local;
// P->PV-A transpose = 4 v_permlane32_swap_b32; row-sums via ones-MFMA (same layout as
// o -> lane-local normalize). KV-tile 64, double-buffered LDS, one barrier per tile,
// prefetch-before-compute. XOR-swizzled tiles (blk ^= row&7) with pre-swizzled global
// source (gload_lds dest stays linear). Grid 1024, XCD swizzle.
// OCML __builtin_exp2f (proven green r3/r6; amdgcn_exp2f implicated in r7 failure).
// No setprio (r6 A/B: +2us on lockstep 4-wave blocks).
__global__ __launch_bounds__(256, 3) void flash_attn8(const _Float16* __restrict__ Q,
                                                      const _Float16* __restrict__ Kp,
                                                      const _Float16* __restrict__ Vt,
                                                      _Float16* __restrict__ O) {
  __shared__ _Float16 Ksb[2 * 64 * 64];  // [buf][kv64][d64], 16B-blk XOR by kv&7
  __shared__ _Float16 Vsb[2 * 64 * 64];  // [buf][d64][kv64], 16B-blk XOR by d&7
  const int tid = threadIdx.x;
  const int wave = tid >> 6, lane = tid & 63;
  const int l31 = lane & 31, hi = lane >> 5, x7 = lane & 7;

  // XCD-aware swizzle: 1024 blocks % 8 == 0 -> bijective chunked remap
  const int flat = blockIdx.x;
  const int nf = (flat & 7) * 128 + (flat >> 3);
  const int qblk = nf & 31, bh = nf >> 5;
  const int b = bh >> 3, h = bh & 7;

  const size_t qrow0 = (size_t)b * SQ + qblk * 128 + wave * 32;
  const _Float16* qptr = Q + qrow0 * INNER + h * DH;
  const _Float16* kbase = Kp + (size_t)b * SKV * INNER + h * DH;
  const _Float16* vbase = Vt + (size_t)bh * DH * SKV;

  // staging: linear LDS dest (tid*16B), pre-swizzled global src (blk ^= row&7)
  const int kr = tid >> 3;
  const int kb = (tid & 7) ^ (kr & 7);
  const _Float16* kg = kbase + (size_t)kr * INNER + kb * 8;
  const _Float16* vg = vbase + (size_t)kr * SKV + kb * 8;

#define STAGE_KV(bi, tt)                                                        \
  do {                                                                          \
    _Float16* _kl = Ksb + (bi) * 4096 + tid * 8;                                \
    _Float16* _vl = Vsb + (bi) * 4096 + tid * 8;                                \
    GLD16(kg + (size_t)((tt) * 64) * INNER, _kl);                               \
    GLD16(kg + (size_t)((tt) * 64 + 32) * INNER, _kl + 2048);                   \
    GLD16(vg + (tt) * 64, _vl);                                                 \
    GLD16(vg + (size_t)32 * SKV + (tt) * 64, _vl + 2048);                       \
  } while (0)

  half8 aq[4];
#pragma unroll
  for (int i = 0; i < 4; ++i)
    aq[i] = *(const half8*)(qptr + (size_t)l31 * INNER + i * 16 + hi * 8);

  int koff[4], voffB[4];
#pragma unroll
  for (int i = 0; i < 4; ++i)
    koff[i] = l31 * 64 + (((i * 2 + hi) ^ x7) << 3);
#pragma unroll
  for (int j = 0; j < 4; ++j)
    voffB[j] = l31 * 64 + (((j * 2 + hi) ^ x7) << 3);

  half8 ones;
#pragma unroll
  for (int j = 0; j < 8; ++j) ones[j] = (_Float16)1.0f;

  f32x16 o0 = {}, o1 = {}, osum = {};

  STAGE_KV(0, 0);

  for (int t = 0; t < SKV / 64; ++t) {
    __syncthreads();
    if (t < SKV / 64 - 1) STAGE_KV((t + 1) & 1, t + 1);
    const _Float16* ks = Ksb + (t & 1) * 4096;
    const _Float16* vs = Vsb + (t & 1) * 4096;

#pragma unroll
    for (int c2 = 0; c2 < 2; ++c2) {
      half8 ak[4];
#pragma unroll
      for (int i = 0; i < 4; ++i)
        ak[i] = *(const half8*)(ks + c2 * 2048 + koff[i]);

      f32x16 st = {};
#pragma unroll
      for (int i = 0; i < 4; ++i) st = MFMA32(ak[i], aq[i], st);

      unsigned w[8];
#pragma unroll
      for (int j = 0; j < 8; ++j) {
        float plo = __builtin_exp2f(st[2 * j]);
        float phi = __builtin_exp2f(st[2 * j + 1]);
        w[j] = __builtin_bit_cast(unsigned, __builtin_amdgcn_cvt_pkrtz(plo, phi));
      }
      PLSWAP(w[0], w[2]);
      PLSWAP(w[1], w[3]);
      PLSWAP(w[4], w[6]);
      PLSWAP(w[5], w[7]);
      uint4v u0 = {w[0], w[1], w[2], w[3]};
      uint4v u1 = {w[4], w[5], w[6], w[7]};
      half8 A0 = __builtin_bit_cast(half8, u0);
      half8 A1 = __builtin_bit_cast(half8, u1);

      osum = MFMA32(A0, ones, osum);
      osum = MFMA32(A1, ones, osum);

      {
        half8 bv00 = *(const half8*)(vs + 0 * 2048 + voffB[c2 * 2 + 0]);
        half8 bv10 = *(const half8*)(vs + 1 * 2048 + voffB[c2 * 2 + 0]);
        o0 = MFMA32(A0, bv00, o0);
        o1 = MFMA32(A0, bv10, o1);
        half8 bv01 = *(const half8*)(vs + 0 * 2048 + voffB[c2 * 2 + 1]);
        half8 bv11 = *(const half8*)(vs + 1 * 2048 + voffB[c2 * 2 + 1]);
        o0 = MFMA32(A1, bv01, o0);
        o1 = MFMA32(A1, bv11, o1);
      }
    }
  }

  float inv16[16];
#pragma unroll
  for (int r = 0; r < 16; ++r) inv16[r] = 1.0f / osum[r];

  _Float16* op = O + qrow0 * INNER + h * DH;
#pragma unroll
  for (int r = 0; r < 16; ++r) {
    const int q = (r & 3) + 8 * (r >> 2) + 4 * hi;
    op[(size_t)q * INNER + l31] = (_Float16)(o0[r] * inv16[r]);
    op[(size_t)q * INNER + 32 + l31] = (_Float16)(o1[r] * inv16[r]);
  }
#undef STAGE_KV
}

// ---------------------------------------------------------------- launcher
extern "C" void kernel_launch(void* const* d_in, const int* in_sizes, int n_in,
                              void* d_out, int out_size, void* d_ws, size_t ws_size,
                              hipStream_t stream) {
  const float* x   = (const float*)d_in[0];
  const float* ctx = (const float*)d_in[1];
  const float* Wq  = (const float*)d_in[2];
  const float* Wk  = (const float*)d_in[3];
  const float* Wv  = (const float*)d_in[4];
  const float* Wo  = (const float*)d_in[5];
  const float* bo  = (const float*)d_in[6];
  float* out = (float*)d_out;

  const size_t NX = (size_t)BATCH * SQ * QD;   // 16.7M
  const size_t NC = (size_t)BATCH * SKV * CD;  // 3.1M

  _Float16* ws = (_Float16*)d_ws;
  _Float16* xh   = ws;                                   // [16384,1024] fp16
  _Float16* ctxh = xh + NX;                              // [4096,768]
  _Float16* wqt  = ctxh + NC;                            // [512,1024]
  _Float16* wkvt = wqt + (size_t)INNER * QD;             // [1024,768] (k rows, then v)
  _Float16* wot  = wkvt + (size_t)2 * INNER * CD;        // [1024,512]
  _Float16* qh   = wot + (size_t)QD * INNER;             // [16384,512]
  _Float16* kh   = qh + (size_t)BATCH * SQ * INNER;      // [4096,512]
  _Float16* vth  = kh + (size_t)BATCH * SKV * INNER;     // [4,8,64,1024]
  _Float16* aoh  = xh;  // alias: xh dead after proj_fused; aoh (8.4M) fits in NX

  // cast (9728 blocks) + weight transposes (4096 blocks) in one launch
  prep<<<dim3((unsigned)((NX + NC) / 2048) + 4096), 256, 0, stream>>>(
      x, ctx, Wq, Wk, Wv, Wo, xh, ctxh, wqt, wkvt, wot);

  // fused Q + KV projections (768 blocks, XCD-local A-stripes)
  proj_fused<<<dim3(768), 256, 0, stream>>>(xh, ctxh, wqt, wkvt, qh, kh, vth);

  // attention
  flash_attn8<<<dim3(BATCH * NH * SQ / 128), 256, 0, stream>>>(qh, kh, vth, aoh);

  // output projection + bias, fp32 out (1024 blocks, XCD-local A-stripes)
  gemm_out<<<dim3(1024), 256, 0, stream>>>(aoh, wot, out, bo);
}

// Round 10
// 255.556 us; speedup vs baseline: 1.0794x; 1.0266x over previous
//
#include <hip/hip_runtime.h>

#define SQ 4096
#define SKV 1024
#define BATCH 4
#define NH 8
#define DH 64
#define QD 1024
#define CD 768
#define INNER 512

typedef _Float16 half8 __attribute__((ext_vector_type(8)));
typedef _Float16 half4v __attribute__((ext_vector_type(4)));
typedef float floatx4 __attribute__((ext_vector_type(4)));
typedef float f32x16 __attribute__((ext_vector_type(16)));
typedef unsigned int uint4v __attribute__((ext_vector_type(4)));

#define MFMA16(a, b, c) __builtin_amdgcn_mfma_f32_16x16x32_f16(a, b, c, 0, 0, 0)
#define MFMA32(a, b, c) __builtin_amdgcn_mfma_f32_32x32x16_f16(a, b, c, 0, 0, 0)

// v_permlane32_swap_b32: a' = {a.lo31, b.lo31}, b' = {a.hi31, b.hi31}
#define PLSWAP(a, b) asm("v_permlane32_swap_b32 %0, %1" : "+v"(a), "+v"(b))

// async global->LDS, 16B per lane; LDS dest = wave-uniform base + lane*16
#define GLD16(gptr, lptr)                                                            \
  __builtin_amdgcn_global_load_lds(                                                  \
      (const __attribute__((address_space(1))) unsigned int*)(const void*)(gptr),    \
      (__attribute__((address_space(3))) unsigned int*)(void*)(lptr), 16, 0, 0)

// ---------------------------------------------------------------- weight transposes
// 4 weight transposes in one launch; z selects the matrix. (r0-green form.)
// src [R,C] fp32 -> dst [C,R] fp16.
__global__ __launch_bounds__(256) void transpose_all(const float* __restrict__ Wq,
                                                     const float* __restrict__ Wk,
                                                     const float* __restrict__ Wv,
                                                     const float* __restrict__ Wo,
                                                     _Float16* __restrict__ wqt,
                                                     _Float16* __restrict__ wkvt,
                                                     _Float16* __restrict__ wot) {
  __shared__ float tile[32][33];
  const int z = blockIdx.z;
  const float* src; _Float16* dst; int R, C;
  if (z == 0)      { src = Wq; dst = wqt;                        R = QD;    C = INNER; }
  else if (z == 1) { src = Wk; dst = wkvt;                       R = CD;    C = INNER; }
  else if (z == 2) { src = Wv; dst = wkvt + (size_t)INNER * CD;  R = CD;    C = INNER; }
  else             { src = Wo; dst = wot;                        R = INNER; C = QD;   }
  const int c0 = blockIdx.x * 32, r0 = blockIdx.y * 32;
  if (c0 >= C || r0 >= R) return;
  const int tx = threadIdx.x & 31, ty = threadIdx.x >> 5;
#pragma unroll
  for (int i = 0; i < 32; i += 8)
    tile[ty + i][tx] = src[(size_t)(r0 + ty + i) * C + c0 + tx];
  __syncthreads();
#pragma unroll
  for (int i = 0; i < 32; i += 8)
    dst[(size_t)(c0 + ty + i) * R + r0 + tx] = (_Float16)tile[tx][ty + i];
}

// ---------------------------------------------------------------- dbuf GEMM body
// C[M,N] = A[M,K] @ B[K,N], B transposed (Bt[N,K], fp16 row-major).
// A row-major: fp32 if AF32 (staged raw into LDS, converted at frag-read — r0-green
// path; numerically identical RTNE to a separate cast kernel) else fp16.
// Tile 128x128, BK=32, 4 waves (2x2 of 64x64). Double-buffered LDS, one
// __syncthreads per k-step, prefetch-before-compute (r8-green loop).
// Block mapping is XCD-LOCAL (see launch sites): all n-blocks of one A-stripe land
// on the SAME XCD so its private L2 fetches the stripe once (r8: -13.5us).
// MODE 2: fp32 + bias. MODE 3: fp16 out scaled by 0.125*log2(e).
// MODE 4: merged k/v epilogue — n<512 -> kh row-major [M,512]; n>=512 -> vT scatter.
template <int MODE, int AF32>
__device__ __forceinline__ void gemm_body(const void* __restrict__ Aany,
                                          const _Float16* __restrict__ Bt,
                                          void* __restrict__ Cout,
                                          void* __restrict__ Cout2,
                                          const float* __restrict__ bias,
                                          int M, int N, int K, int bx, int by,
                                          void* AsRaw, _Float16* Bs) {
  float* As32 = (float*)AsRaw;
  _Float16* As16 = (_Float16*)AsRaw;
  const int tid = threadIdx.x;
  const int wave = tid >> 6, lane = tid & 63;
  const int quad = lane >> 4, l16 = lane & 15;
  const int wm = (wave >> 1) * 64, wn = (wave & 1) * 64;
  const size_t n0 = (size_t)bx * 128, m0 = (size_t)by * 128;

  floatx4 acc[4][4] = {};

  const float* a32g = (const float*)Aany + (m0 + (tid >> 3)) * (size_t)K + (tid & 7) * 4;
  const _Float16* a16g = (const _Float16*)Aany + (m0 + (tid >> 2)) * (size_t)K + (tid & 3) * 8;
  const _Float16* bg = Bt + (n0 + (tid >> 2)) * (size_t)K + (tid & 3) * 8;

#define GSTAGE(bi, k0)                                                        \
  do {                                                                        \
    if (AF32) {                                                               \
      GLD16(a32g + (k0), As32 + (bi)*4096 + tid * 4);                         \
      GLD16(a32g + (k0) + (size_t)32 * K, As32 + (bi)*4096 + tid * 4 + 1024); \
      GLD16(a32g + (k0) + (size_t)64 * K, As32 + (bi)*4096 + tid * 4 + 2048); \
      GLD16(a32g + (k0) + (size_t)96 * K, As32 + (bi)*4096 + tid * 4 + 3072); \
    } else {                                                                  \
      GLD16(a16g + (k0), As16 + (bi)*4096 + tid * 8);                         \
      GLD16(a16g + (k0) + (size_t)64 * K, As16 + (bi)*4096 + tid * 8 + 2048); \
    }                                                                         \
    GLD16(bg + (k0), Bs + (bi)*4096 + tid * 8);                               \
    GLD16(bg + (k0) + (size_t)64 * K, Bs + (bi)*4096 + tid * 8 + 2048);       \
  } while (0)

  const int NT = K / 32;
  GSTAGE(0, 0);
  for (int t = 0; t < NT; ++t) {
    __syncthreads();  // drains tile-t loads (issued one compute phase ago);
                      // also fences: prev readers of buf[(t+1)&1] are done
    if (t + 1 < NT) GSTAGE((t + 1) & 1, (t + 1) * 32);
    const int bo = (t & 1) * 4096;

    half8 af[4], bf[4];
#pragma unroll
    for (int mt = 0; mt < 4; ++mt) {
      const int row = wm + mt * 16 + l16;
      if (AF32) {
        floatx4 x0 = *(const floatx4*)(As32 + bo + row * 32 + quad * 8);
        floatx4 x1 = *(const floatx4*)(As32 + bo + row * 32 + quad * 8 + 4);
        half8 tt;
#pragma unroll
        for (int i = 0; i < 4; ++i) { tt[i] = (_Float16)x0[i]; tt[4 + i] = (_Float16)x1[i]; }
        af[mt] = tt;
      } else {
        af[mt] = *(const half8*)(As16 + bo + row * 32 + quad * 8);
      }
    }
#pragma unroll
    for (int nt = 0; nt < 4; ++nt)
      bf[nt] = *(const half8*)(Bs + bo + (wn + nt * 16 + l16) * 32 + quad * 8);
    __builtin_amdgcn_s_setprio(1);
#pragma unroll
    for (int mt = 0; mt < 4; ++mt)
#pragma unroll
      for (int nt = 0; nt < 4; ++nt)
        acc[mt][nt] = MFMA16(af[mt], bf[nt], acc[mt][nt]);
    __builtin_amdgcn_s_setprio(0);
  }
#undef GSTAGE

  // epilogue: C/D layout row = quad*4+r, col = l16
  if (MODE == 3) {
    _Float16* C = (_Float16*)Cout;
    // fold softmax scale (1/8) and log2(e) into Q so attention uses exp2
    const float sc = 0.125f * 1.44269504088896f;
#pragma unroll
    for (int mt = 0; mt < 4; ++mt) {
      const size_t row = m0 + wm + mt * 16 + quad * 4;
#pragma unroll
      for (int nt = 0; nt < 4; ++nt) {
        const size_t col = n0 + wn + nt * 16 + l16;
#pragma unroll
        for (int r = 0; r < 4; ++r)
          C[(row + r) * N + col] = (_Float16)(acc[mt][nt][r] * sc);
      }
    }
  } else if (MODE == 4) {
    if (n0 < INNER) {  // K half: row-major [M, INNER]
      _Float16* C = (_Float16*)Cout;
#pragma unroll
      for (int mt = 0; mt < 4; ++mt) {
        const size_t row = m0 + wm + mt * 16 + quad * 4;
#pragma unroll
        for (int nt = 0; nt < 4; ++nt) {
          const size_t col = n0 + wn + nt * 16 + l16;
#pragma unroll
          for (int r = 0; r < 4; ++r)
            C[(row + r) * INNER + col] = (_Float16)acc[mt][nt][r];
        }
      }
    } else {  // V half: scatter to vT[b][h][d][kv]
      _Float16* C = (_Float16*)Cout2;
      const int b = (int)(m0 >> 10);
#pragma unroll
      for (int mt = 0; mt < 4; ++mt) {
        const int kvb = (int)(m0 & 1023) + wm + mt * 16 + quad * 4;
#pragma unroll
        for (int nt = 0; nt < 4; ++nt) {
          const int col = (int)(n0 - INNER + wn + nt * 16 + l16);
          const int h = col >> 6, d = col & 63;
          half4v pk;
#pragma unroll
          for (int r = 0; r < 4; ++r) pk[r] = (_Float16)acc[mt][nt][r];
          *(half4v*)(C + (size_t)((b * NH + h) * DH + d) * SKV + kvb) = pk;
        }
      }
    }
  } else {
    float* C = (float*)Cout;
#pragma unroll
    for (int mt = 0; mt < 4; ++mt) {
      const size_t row = m0 + wm + mt * 16 + quad * 4;
#pragma unroll
      for (int nt = 0; nt < 4; ++nt) {
        const size_t col = n0 + wn + nt * 16 + l16;
        const float bb = bias[col];
#pragma unroll
        for (int r = 0; r < 4; ++r)
          C[(row + r) * N + col] = acc[mt][nt][r] + bb;
      }
    }
  }
}

// ---------------------------------------------------------------- fused projections
// Q-proj (512 blocks) + KV-proj (256 blocks) in one 768-block launch, reading
// fp32 x/ctx DIRECTLY (AF32 path — kills the cast kernel's 74 MB round-trip).
// XCD-local mapping (r8-proven): xcd = b&7 owns a contiguous band of m-stripes;
// j%3 interleaves {Q,Q,KV} within the XCD -> A-stripes fetched once per XCD L2.
// LDS 48 KB (As32 dbuf 32K + Bs dbuf 16K) -> 3 blocks/CU; grid 768 = exactly 3/CU.
__global__ __launch_bounds__(256) void proj_fused(const float* __restrict__ x,
                                                  const float* __restrict__ ctx,
                                                  const _Float16* __restrict__ wqt,
                                                  const _Float16* __restrict__ wkvt,
                                                  _Float16* __restrict__ qh,
                                                  _Float16* __restrict__ kh,
                                                  _Float16* __restrict__ vth) {
  __shared__ float As32[2 * 128 * 32];
  __shared__ _Float16 Bs[2 * 128 * 32];
  const int b = blockIdx.x;
  const int xcd = b & 7, j = b >> 3;
  const int seg = j % 3;
  if (seg == 2) {  // KV: M=4096, N=1024 (k|v), K=768; stripes 0..31, n 0..7
    const int jkv = j / 3;  // 0..31
    gemm_body<4, 1>((const void*)ctx, wkvt, kh, vth, nullptr, BATCH * SKV,
                    2 * INNER, CD, jkv & 7, xcd * 4 + (jkv >> 3), As32, Bs);
  } else {  // Q: M=16384, N=512, K=1024 (scale folded); stripes 0..127, n 0..3
    const int jq = (j / 3) * 2 + seg;  // 0..63
    gemm_body<3, 1>((const void*)x, wqt, qh, nullptr, nullptr, BATCH * SQ,
                    INNER, QD, jq & 3, xcd * 16 + (jq >> 2), As32, Bs);
  }
}

// ---------------------------------------------------------------- output projection
// 1024 blocks, XCD-local: xcd = b&7 owns aoh m-stripes [xcd*16, xcd*16+16).
__global__ __launch_bounds__(256) void gemm_out(const _Float16* __restrict__ A,
                                                const _Float16* __restrict__ Bt,
                                                float* __restrict__ Cout,
                                                const float* __restrict__ bias) {
  __shared__ _Float16 As16[2 * 128 * 32];
  __shared__ _Float16 Bs[2 * 128 * 32];
  const int b = blockIdx.x;
  const int xcd = b & 7, i = b >> 3;  // i: 0..127
  gemm_body<2, 0>((const void*)A, Bt, Cout, nullptr, bias, BATCH * SQ, QD, INNER,
                  i & 7, xcd * 16 + (i >> 3), As16, Bs);
}

// ---------------------------------------------------------------- flash attention v8
// (byte-identical to r8-green.) 32x32x16 MFMA. Swapped QK^T (S^T = K·Q^T): lane owns
// one q-row, softmax lane-local; P->PV-A transpose = 4 v_permlane32_swap_b32;
// row-sums via ones-MFMA (same layout as o -> lane-local normalize). KV-tile 64,
// double-buffered LDS, one barrier per tile, prefetch-before-compute. XOR-swizzled
// tiles (blk ^= row&7) with pre-swizzled global source. Grid 1024, XCD swizzle.
// exp path: __builtin_exp2f ONLY (amdgcn builtin and raw asm both produced ~0.1
// absmax failures in r7/r9 — TRANS-op hazard not honored around opaque asm).
// No setprio (r4-cur vs r6-cur A/B: +3us on this lockstep 4-wave kernel).
__global__ __launch_bounds__(256, 3) void flash_attn8(const _Float16* __restrict__ Q,
                                                      const _Float16* __restrict__ Kp,
                                                      const _Float16* __restrict__ Vt,
                                                      _Float16* __restrict__ O) {
  __shared__ _Float16 Ksb[2 * 64 * 64];  // [buf][kv64][d64], 16B-blk XOR by kv&7
  __shared__ _Float16 Vsb[2 * 64 * 64];  // [buf][d64][kv64], 16B-blk XOR by d&7
  const int tid = threadIdx.x;
  const int wave = tid >> 6, lane = tid & 63;
  const int l31 = lane & 31, hi = lane >> 5, x7 = lane & 7;

  // XCD-aware swizzle: 1024 blocks % 8 == 0 -> bijective chunked remap
  const int flat = blockIdx.x;
  const int nf = (flat & 7) * 128 + (flat >> 3);
  const int qblk = nf & 31, bh = nf >> 5;
  const int b = bh >> 3, h = bh & 7;

  const size_t qrow0 = (size_t)b * SQ + qblk * 128 + wave * 32;
  const _Float16* qptr = Q + qrow0 * INNER + h * DH;
  const _Float16* kbase = Kp + (size_t)b * SKV * INNER + h * DH;
  const _Float16* vbase = Vt + (size_t)bh * DH * SKV;

  // staging: linear LDS dest (tid*16B), pre-swizzled global src (blk ^= row&7)
  const int kr = tid >> 3;
  const int kb = (tid & 7) ^ (kr & 7);
  const _Float16* kg = kbase + (size_t)kr * INNER + kb * 8;
  const _Float16* vg = vbase + (size_t)kr * SKV + kb * 8;

#define STAGE_KV(bi, tt)                                                        \
  do {                                                                          \
    _Float16* _kl = Ksb + (bi) * 4096 + tid * 8;                                \
    _Float16* _vl = Vsb + (bi) * 4096 + tid * 8;                                \
    GLD16(kg + (size_t)((tt) * 64) * INNER, _kl);                               \
    GLD16(kg + (size_t)((tt) * 64 + 32) * INNER, _kl + 2048);                   \
    GLD16(vg + (tt) * 64, _vl);                                                 \
    GLD16(vg + (size_t)32 * SKV + (tt) * 64, _vl + 2048);                       \
  } while (0)

  half8 aq[4];
#pragma unroll
  for (int i = 0; i < 4; ++i)
    aq[i] = *(const half8*)(qptr + (size_t)l31 * INNER + i * 16 + hi * 8);

  int koff[4], voffB[4];
#pragma unroll
  for (int i = 0; i < 4; ++i)
    koff[i] = l31 * 64 + (((i * 2 + hi) ^ x7) << 3);
#pragma unroll
  for (int j = 0; j < 4; ++j)
    voffB[j] = l31 * 64 + (((j * 2 + hi) ^ x7) << 3);

  half8 ones;
#pragma unroll
  for (int j = 0; j < 8; ++j) ones[j] = (_Float16)1.0f;

  f32x16 o0 = {}, o1 = {}, osum = {};

  STAGE_KV(0, 0);

  for (int t = 0; t < SKV / 64; ++t) {
    __syncthreads();
    if (t < SKV / 64 - 1) STAGE_KV((t + 1) & 1, t + 1);
    const _Float16* ks = Ksb + (t & 1) * 4096;
    const _Float16* vs = Vsb + (t & 1) * 4096;

#pragma unroll
    for (int c2 = 0; c2 < 2; ++c2) {
      half8 ak[4];
#pragma unroll
      for (int i = 0; i < 4; ++i)
        ak[i] = *(const half8*)(ks + c2 * 2048 + koff[i]);

      f32x16 st = {};
#pragma unroll
      for (int i = 0; i < 4; ++i) st = MFMA32(ak[i], aq[i], st);

      unsigned w[8];
#pragma unroll
      for (int j = 0; j < 8; ++j) {
        float plo = __builtin_exp2f(st[2 * j]);
        float phi = __builtin_exp2f(st[2 * j + 1]);
        w[j] = __builtin_bit_cast(unsigned, __builtin_amdgcn_cvt_pkrtz(plo, phi));
      }
      PLSWAP(w[0], w[2]);
      PLSWAP(w[1], w[3]);
      PLSWAP(w[4], w[6]);
      PLSWAP(w[5], w[7]);
      uint4v u0 = {w[0], w[1], w[2], w[3]};
      uint4v u1 = {w[4], w[5], w[6], w[7]};
      half8 A0 = __builtin_bit_cast(half8, u0);
      half8 A1 = __builtin_bit_cast(half8, u1);

      osum = MFMA32(A0, ones, osum);
      osum = MFMA32(A1, ones, osum);

      {
        half8 bv00 = *(const half8*)(vs + 0 * 2048 + voffB[c2 * 2 + 0]);
        half8 bv10 = *(const half8*)(vs + 1 * 2048 + voffB[c2 * 2 + 0]);
        o0 = MFMA32(A0, bv00, o0);
        o1 = MFMA32(A0, bv10, o1);
        half8 bv01 = *(const half8*)(vs + 0 * 2048 + voffB[c2 * 2 + 1]);
        half8 bv11 = *(const half8*)(vs + 1 * 2048 + voffB[c2 * 2 + 1]);
        o0 = MFMA32(A1, bv01, o0);
        o1 = MFMA32(A1, bv11, o1);
      }
    }
  }

  float inv16[16];
#pragma unroll
  for (int r = 0; r < 16; ++r) inv16[r] = 1.0f / osum[r];

  _Float16* op = O + qrow0 * INNER + h * DH;
#pragma unroll
  for (int r = 0; r < 16; ++r) {
    const int q = (r & 3) + 8 * (r >> 2) + 4 * hi;
    op[(size_t)q * INNER + l31] = (_Float16)(o0[r] * inv16[r]);
    op[(size_t)q * INNER + 32 + l31] = (_Float16)(o1[r] * inv16[r]);
  }
#undef STAGE_KV
}

// ---------------------------------------------------------------- launcher
extern "C" void kernel_launch(void* const* d_in, const int* in_sizes, int n_in,
                              void* d_out, int out_size, void* d_ws, size_t ws_size,
                              hipStream_t stream) {
  const float* x   = (const float*)d_in[0];
  const float* ctx = (const float*)d_in[1];
  const float* Wq  = (const float*)d_in[2];
  const float* Wk  = (const float*)d_in[3];
  const float* Wv  = (const float*)d_in[4];
  const float* Wo  = (const float*)d_in[5];
  const float* bo  = (const float*)d_in[6];
  float* out = (float*)d_out;

  _Float16* ws = (_Float16*)d_ws;
  _Float16* wqt  = ws;                                   // [512,1024]
  _Float16* wkvt = wqt + (size_t)INNER * QD;             // [1024,768] (k rows, then v)
  _Float16* wot  = wkvt + (size_t)2 * INNER * CD;        // [1024,512]
  _Float16* qh   = wot + (size_t)QD * INNER;             // [16384,512]
  _Float16* kh   = qh + (size_t)BATCH * SQ * INNER;      // [4096,512]
  _Float16* vth  = kh + (size_t)BATCH * SKV * INNER;     // [4,8,64,1024]
  _Float16* aoh  = vth + (size_t)BATCH * SKV * INNER;    // [16384,512]

  // weight transposes only (cast kernel deleted — proj reads fp32 directly)
  transpose_all<<<dim3(32, 32, 4), 256, 0, stream>>>(Wq, Wk, Wv, Wo, wqt, wkvt, wot);

  // fused Q + KV projections (768 blocks, XCD-local A-stripes, fp32 A)
  proj_fused<<<dim3(768), 256, 0, stream>>>(x, ctx, wqt, wkvt, qh, kh, vth);

  // attention
  flash_attn8<<<dim3(BATCH * NH * SQ / 128), 256, 0, stream>>>(qh, kh, vth, aoh);

  // output projection + bias, fp32 out (1024 blocks, XCD-local A-stripes)
  gemm_out<<<dim3(1024), 256, 0, stream>>>(aoh, wot, out, bo);
}